// Round 4
// baseline (155.767 us; speedup 1.0000x reference)
//
#include <hip/hip_runtime.h>

// StateSpaceDiffusionModel — MFMA, one-barrier-per-chunk formulation.
//
// Scalar collapse (HW-verified R2/R3):
//   r_t = u_t + sum_j w_j r_{t-1-j},  y_t = sum_j g_j r_{t-j}   (order 64)
// Chunk=64 (= IIR order) => p' (next state window) = r, and:
//   p' = T·p + S·u     T = S·W (general 64x64, precomputed via MFMA), S Toeplitz (taps s)
//   y  = G2·p' + G1·p  G2[t][j]=g_{t-j}, G1[t][j]=g_{t-j+64}  (Toeplitz)
// One LDS roundtrip (p', double-buffered) + ONE barrier per chunk.
// Precision: recurrence path = 3-product hi/lo splits; y path = GH-only
// (error non-accumulating); per-chunk cvt = Dekker-trunc split (exact lo).
// MFMA layouts (verified R3): A[m][k]: m=lane&15, k=(lane>>4)*8+j+32tk;
// B[k][n]: k same, n=lane&15;  C[m][n]: n=lane&15, m=(lane>>4)*4+reg.

namespace {

constexpr int kH = 512;
constexpr int kL = 2048;
constexpr int kChunks = 32;
constexpr int kTS = 68;   // Tbuf row stride (floats)
constexpr int kPS = 68;   // Pbuf row stride (floats)

typedef __attribute__((ext_vector_type(8))) short bf16x8;
typedef __attribute__((ext_vector_type(4))) float f32x4;
typedef __attribute__((ext_vector_type(4))) unsigned int u32x4;

__device__ inline unsigned short bf16_rne(float x) {
  unsigned int u = __float_as_uint(x);
  unsigned int r = u + 0x7FFFu + ((u >> 16) & 1u);
  return (unsigned short)(r >> 16);
}
__device__ inline float bf16f(unsigned short h) {
  return __uint_as_float(((unsigned int)h) << 16);
}
// pack: low16 = hi16(a), high16 = hi16(b)
__device__ inline unsigned pack_hi16(unsigned a, unsigned b) {
#if __has_builtin(__builtin_amdgcn_perm)
  return __builtin_amdgcn_perm(b, a, 0x07060302u);
#else
  return (b & 0xFFFF0000u) | (a >> 16);
#endif
}
// Dekker split of 8 f32 into hi/lo bf16x8; hi = truncation, lo = exact residual
__device__ inline void dekker8(const f32x4 a, const f32x4 b, bf16x8& hh, bf16x8& ll) {
  const unsigned ua0 = __float_as_uint(a[0]), ua1 = __float_as_uint(a[1]);
  const unsigned ua2 = __float_as_uint(a[2]), ua3 = __float_as_uint(a[3]);
  const unsigned ub0 = __float_as_uint(b[0]), ub1 = __float_as_uint(b[1]);
  const unsigned ub2 = __float_as_uint(b[2]), ub3 = __float_as_uint(b[3]);
  u32x4 hu, lu;
  hu[0] = pack_hi16(ua0, ua1);
  hu[1] = pack_hi16(ua2, ua3);
  hu[2] = pack_hi16(ub0, ub1);
  hu[3] = pack_hi16(ub2, ub3);
  const float l0 = a[0] - __uint_as_float(ua0 & 0xFFFF0000u);
  const float l1 = a[1] - __uint_as_float(ua1 & 0xFFFF0000u);
  const float l2 = a[2] - __uint_as_float(ua2 & 0xFFFF0000u);
  const float l3 = a[3] - __uint_as_float(ua3 & 0xFFFF0000u);
  const float l4 = b[0] - __uint_as_float(ub0 & 0xFFFF0000u);
  const float l5 = b[1] - __uint_as_float(ub1 & 0xFFFF0000u);
  const float l6 = b[2] - __uint_as_float(ub2 & 0xFFFF0000u);
  const float l7 = b[3] - __uint_as_float(ub3 & 0xFFFF0000u);
  lu[0] = pack_hi16(__float_as_uint(l0), __float_as_uint(l1));
  lu[1] = pack_hi16(__float_as_uint(l2), __float_as_uint(l3));
  lu[2] = pack_hi16(__float_as_uint(l4), __float_as_uint(l5));
  lu[3] = pack_hi16(__float_as_uint(l6), __float_as_uint(l7));
  hh = __builtin_bit_cast(bf16x8, hu);
  ll = __builtin_bit_cast(bf16x8, lu);
}

#define MFMA(A, B, C) __builtin_amdgcn_mfma_f32_16x16x32_bf16((A), (B), (C), 0, 0, 0)

__global__ __launch_bounds__(256, 2)
void ssm_mfma_kernel(const float* __restrict__ u,
                     const float* __restrict__ kin,
                     float* __restrict__ y) {
  const int h    = blockIdx.x;
  const int tid  = threadIdx.x;
  const int wq   = tid >> 6;
  const int lane = tid & 63;
  const int ln16 = lane & 15;
  const int quad = lane >> 4;

  __shared__ __align__(16) float Tbuf[64][kTS];      // T = S·W, fp32
  __shared__ __align__(16) float Pbuf[2][16][kPS];   // p' transposed [batch][time]
  __shared__ float wArr[64], sArr[64], gArr[64], tmpA[64], cArr[64];

  // ---------------- taps (HW-verified R2/R3) -------------------------------
  float kv = 0.f, kc = 0.f, kn = 0.f, cc = 0.f;
  if (tid < 64) {
    kv = kin[h * 64 + tid];
    kc = fminf(fmaxf(kv, 0.0625f), 1.0f);
    tmpA[tid] = kc;
  }
  __syncthreads();
  if (tid < 64) {
    float ks = 0.f;
    for (int j = 0; j < 64; ++j) ks += tmpA[j];
    kn = kc / ks;
    cc = 1.0f / (1.0f + kn);
    cArr[tid] = cc;
  }
  __syncthreads();
  if (tid < 64) {
    float P = 1.0f;
    for (int j = 0; j < tid; ++j) P *= cArr[j];
    wArr[tid] = (tid < 63) ? (kn * cc * P) : P;
    gArr[tid] = kv * P;
    if (tid == 0) sArr[0] = 1.0f;
  }
  __syncthreads();
  float acc_s = (tid == 0) ? 1.0f : 0.0f;
  for (int rr = 0; rr < 63; ++rr) {
    if (tid < 64) {
      const float sval = sArr[rr];
      const float coef = (tid > rr) ? wArr[tid - 1 - rr] : 0.0f;
      acc_s = fmaf(coef, sval, acc_s);
      if (tid == rr + 1) sArr[tid] = acc_s;
    }
    __syncthreads();
  }

  // ---------------- one-time A-fragments (S hi/lo, G1H, G2H) ---------------
  const int rA = 16 * wq + ln16;   // this wave's A-row
  bf16x8 SH[2], SL[2], G1H[2], G2H[2];
  #pragma unroll
  for (int tk = 0; tk < 2; ++tk) {
    bf16x8 sh, sl, g1, g2;
    #pragma unroll
    for (int j = 0; j < 8; ++j) {
      const int k = 32 * tk + 8 * quad + j;
      const int d = rA - k;                       // S, G2 index
      const float sv = (d >= 0 && d < 64) ? sArr[d] : 0.0f;
      const unsigned short shh = bf16_rne(sv);
      sh[j] = (short)shh;
      sl[j] = (short)bf16_rne(sv - bf16f(shh));
      g2[j] = (short)bf16_rne((d >= 0 && d < 64) ? gArr[d] : 0.0f);
      const int d1 = d + 64;                      // G1 index
      g1[j] = (short)bf16_rne((d1 >= 0 && d1 < 64) ? gArr[d1] : 0.0f);
    }
    SH[tk] = sh; SL[tk] = sl; G1H[tk] = g1; G2H[tk] = g2;
  }

  // ---------------- T = S·W via MFMA (one-time) ----------------------------
  {
    // W B-frags: W[k][col] = w[63 + k - col], zero outside [0,63]
    f32x4 accT[4];
    #pragma unroll
    for (int nt = 0; nt < 4; ++nt) {
      const int col = 16 * nt + ln16;
      f32x4 t = {};
      #pragma unroll
      for (int tk = 0; tk < 2; ++tk) {
        bf16x8 wh, wl;
        #pragma unroll
        for (int j = 0; j < 8; ++j) {
          const int k = 32 * tk + 8 * quad + j;
          const int idx = 63 + k - col;
          const float wv = (idx >= 0 && idx < 64) ? wArr[idx] : 0.0f;
          const unsigned short whh = bf16_rne(wv);
          wh[j] = (short)whh;
          wl[j] = (short)bf16_rne(wv - bf16f(whh));
        }
        t = MFMA(SH[tk], wh, t);
        t = MFMA(SH[tk], wl, t);
        t = MFMA(SL[tk], wh, t);
      }
      accT[nt] = t;
    }
    #pragma unroll
    for (int nt = 0; nt < 4; ++nt)
      #pragma unroll
      for (int reg = 0; reg < 4; ++reg)
        Tbuf[16 * wq + 4 * quad + reg][16 * nt + ln16] = accT[nt][reg];
  }
  __syncthreads();

  // T A-frags (rows rA), full RNE hi/lo
  bf16x8 TH[2], TL[2];
  #pragma unroll
  for (int tk = 0; tk < 2; ++tk) {
    const f32x4 ta = *(const f32x4*)&Tbuf[rA][32 * tk + 8 * quad];
    const f32x4 tb = *(const f32x4*)&Tbuf[rA][32 * tk + 8 * quad + 4];
    bf16x8 th, tl;
    #pragma unroll
    for (int j = 0; j < 4; ++j) {
      unsigned short x = bf16_rne(ta[j]);
      th[j] = (short)x; tl[j] = (short)bf16_rne(ta[j] - bf16f(x));
      unsigned short z = bf16_rne(tb[j]);
      th[4 + j] = (short)z; tl[4 + j] = (short)bf16_rne(tb[j] - bf16f(z));
    }
    TH[tk] = th; TL[tk] = tl;
  }

  // ---------------- main loop ----------------------------------------------
  const size_t bstr = (size_t)kH * kL;
  const float* ub = u + (size_t)ln16 * bstr + (size_t)h * kL;            // B-frag base
  float* yb = y + (size_t)ln16 * bstr + (size_t)h * kL + 16 * wq + 4 * quad;  // C base

  bf16x8 uHf[2], uLf[2], pH[2], pL[2];
  {
    bf16x8 z;
    #pragma unroll
    for (int j = 0; j < 8; ++j) z[j] = 0;
    pH[0] = z; pH[1] = z; pL[0] = z; pL[1] = z;
  }
  #pragma unroll
  for (int tk = 0; tk < 2; ++tk) {
    const f32x4 a = *(const f32x4*)(ub + 32 * tk + 8 * quad);
    const f32x4 b = *(const f32x4*)(ub + 32 * tk + 8 * quad + 4);
    dekker8(a, b, uHf[tk], uLf[tk]);
  }

  for (int m = 0; m < kChunks; ++m) {
    const int t0 = m * 64;
    // prefetch next chunk's u (f32) early
    f32x4 na0, nb0, na1, nb1;
    if (m + 1 < kChunks) {
      const float* up = ub + t0 + 64 + 8 * quad;
      na0 = *(const f32x4*)(up);
      nb0 = *(const f32x4*)(up + 4);
      na1 = *(const f32x4*)(up + 32);
      nb1 = *(const f32x4*)(up + 32 + 4);
    }

    // ---- p' = S·u + T·p (two independent chains, merged) ----
    f32x4 accSu = {};
    #pragma unroll
    for (int tk = 0; tk < 2; ++tk) {
      accSu = MFMA(SH[tk], uHf[tk], accSu);
      accSu = MFMA(SH[tk], uLf[tk], accSu);
      accSu = MFMA(SL[tk], uHf[tk], accSu);
    }
    f32x4 accTp = {};
    #pragma unroll
    for (int tk = 0; tk < 2; ++tk) {
      accTp = MFMA(TH[tk], pH[tk], accTp);
      accTp = MFMA(TH[tk], pL[tk], accTp);
      accTp = MFMA(TL[tk], pH[tk], accTp);
    }
    const f32x4 accP = accSu + accTp;
    *(f32x4*)&Pbuf[m & 1][ln16][16 * wq + 4 * quad] = accP;   // transposed store

    // ---- y partial: G1·p (old p, before overwrite) ----
    f32x4 accY = {};
    #pragma unroll
    for (int tk = 0; tk < 2; ++tk) {
      accY = MFMA(G1H[tk], pH[tk], accY);
      accY = MFMA(G1H[tk], pL[tk], accY);
    }
    // cvt next u while p' store drains
    if (m + 1 < kChunks) {
      dekker8(na0, nb0, uHf[0], uLf[0]);
      dekker8(na1, nb1, uHf[1], uLf[1]);
    }
    __syncthreads();

    // ---- new p frags from p' (B-layout read + Dekker split) ----
    #pragma unroll
    for (int tk = 0; tk < 2; ++tk) {
      const f32x4 pa = *(const f32x4*)&Pbuf[m & 1][ln16][32 * tk + 8 * quad];
      const f32x4 pb = *(const f32x4*)&Pbuf[m & 1][ln16][32 * tk + 8 * quad + 4];
      dekker8(pa, pb, pH[tk], pL[tk]);
    }
    // ---- y += G2·p' ----
    #pragma unroll
    for (int tk = 0; tk < 2; ++tk) {
      accY = MFMA(G2H[tk], pH[tk], accY);
      accY = MFMA(G2H[tk], pL[tk], accY);
    }
    *(f32x4*)(yb + t0) = accY;
    // WAR safety: Pbuf is double-buffered; chunk m+2's writes to Pbuf[m&1]
    // are ordered after barrier m+1, which follows this chunk's reads.
  }
}

}  // namespace

extern "C" void kernel_launch(void* const* d_in, const int* in_sizes, int n_in,
                              void* d_out, int out_size, void* d_ws, size_t ws_size,
                              hipStream_t stream) {
  const float* u  = (const float*)d_in[0];   // (16, 512, 2048) fp32
  const float* kk = (const float*)d_in[1];   // (1, 512, 64)    fp32
  if (n_in >= 2 && in_sizes[0] < in_sizes[1]) {
    const float* t = u; u = kk; kk = t;
  }
  float* y = (float*)d_out;                  // (16, 512, 2048) fp32
  hipLaunchKernelGGL(ssm_mfma_kernel, dim3(kH), dim3(256), 0, stream, u, kk, y);
}